// Round 4
// baseline (442.036 us; speedup 1.0000x reference)
//
#include <hip/hip_runtime.h>
#include <hip/hip_bf16.h>

#define BB 8
#define NN 4096
#define MM 4096
#define DD 128

typedef float  f32x4 __attribute__((ext_vector_type(4)));
typedef _Float16 f16x8 __attribute__((ext_vector_type(8)));
typedef _Float16 f16x2 __attribute__((ext_vector_type(2)));

__device__ __forceinline__ void async_copy16(const void* g, void* l) {
    __builtin_amdgcn_global_load_lds(
        (const __attribute__((address_space(1))) void*)g,
        (__attribute__((address_space(3))) void*)l, 16, 0, 0);
}

// Fused prep: fp32->f16 convert + exact fp32 squared row norms for BOTH
// inputs, plus init of fwd/bsum/counter. One wave per row (2 floats/lane).
__global__ void prep_all(const float* __restrict__ x, const float* __restrict__ y,
                         _Float16* __restrict__ xh, _Float16* __restrict__ yh,
                         float* __restrict__ x2, float* __restrict__ y2,
                         unsigned int* __restrict__ fwd, float* __restrict__ bsum,
                         unsigned int* __restrict__ counter) {
    int gtid = blockIdx.x * blockDim.x + threadIdx.x;
    if (gtid < BB * MM) fwd[gtid] = 0x7f800000u;  // +inf bits
    if (gtid == 0) { *bsum = 0.0f; *counter = 0u; }

    int wv   = gtid >> 6;
    int lane = threadIdx.x & 63;
    const float* src;
    _Float16* dst;
    float* sq;
    int row;
    if (wv < BB * NN) {
        src = x; dst = xh; sq = x2; row = wv;
    } else {
        src = y; dst = yh; sq = y2; row = wv - BB * NN;
    }
    const float2 v = ((const float2*)src)[(size_t)row * 64 + lane];
    float s = v.x * v.x + v.y * v.y;
    f16x2 h;
    h.x = (_Float16)v.x;
    h.y = (_Float16)v.y;
    ((f16x2*)dst)[(size_t)row * 64 + lane] = h;
    #pragma unroll
    for (int off = 32; off; off >>= 1) s += __shfl_down(s, off, 64);
    if (lane == 0) sq[row] = s;
}

// Main kernel, m97-regime: 128x128 tile, 256 threads (4 waves of 64x64),
// phase = (batch, K-half): stage 16KB x-half + 16KB y-half, 2 barriers/phase.
// LDS 48KB -> 3 blocks/CU (12 waves) so co-resident blocks cover each
// other's staging drains (round-3 lesson: co-residency IS the pipeline).
// XOR swizzle (chunk ^= row&7) keeps ds_read_b128 at the 2-way minimum.
__global__ __launch_bounds__(256, 3)
void chamfer_main(const _Float16* __restrict__ xh, const _Float16* __restrict__ yh,
                  const float* __restrict__ x2, const float* __restrict__ y2,
                  unsigned int* __restrict__ fwd, float* __restrict__ bsum,
                  unsigned int* __restrict__ counter, float* __restrict__ out) {
    __shared__ _Float16 xs[128 * 64];   // 16 KB (one K-half of x-tile)
    __shared__ _Float16 ys[128 * 64];   // 16 KB
    __shared__ float x2s[BB][128];      // 4 KB
    __shared__ float y2s[BB][128];      // 4 KB
    __shared__ float fbuf[2][BB][128];  // 8 KB (wr half, batch, col)
    __shared__ float red[4];
    __shared__ int isLast;

    const int tid  = threadIdx.x;
    const int lane = tid & 63;
    const int wave = tid >> 6;
    const int wr   = wave >> 1;
    const int wc   = wave & 1;
    const int quad = lane >> 4;
    const int l15  = lane & 15;
    const int n0   = blockIdx.x * 128;
    const int m0   = blockIdx.y * 128;

    // staging constants: per round r, row = r*32 + wave*8 + (lane>>3),
    // LDS chunk c' = lane&7, global chunk g = c' ^ (row&7) = (lane&7)^(lane>>3)
    const int srow = wave * 8 + (lane >> 3);
    const int g    = (lane & 7) ^ (lane >> 3);
    const int dstb = wave * 1024 + lane * 16;

    // stage x2/y2 slices for all batches (read in epilogues)
    for (int i = tid; i < BB * 128; i += 256) {
        int b = i >> 7, c = i & 127;
        x2s[b][c] = x2[(size_t)b * NN + n0 + c];
        y2s[b][c] = y2[(size_t)b * MM + m0 + c];
    }

    const float INF = __builtin_inff();
    f32x4 bmin[4][4];
    #pragma unroll
    for (int i = 0; i < 4; ++i)
        #pragma unroll
        for (int j = 0; j < 4; ++j)
            bmin[i][j] = (f32x4){INF, INF, INF, INF};

    for (int b = 0; b < BB; ++b) {
        const char* xg = (const char*)(xh + ((size_t)b * NN + n0) * DD);
        const char* yg = (const char*)(yh + ((size_t)b * MM + m0) * DD);

        f32x4 acc[4][4];
        #pragma unroll
        for (int i = 0; i < 4; ++i)
            #pragma unroll
            for (int j = 0; j < 4; ++j)
                acc[i][j] = (f32x4){0.f, 0.f, 0.f, 0.f};

        #pragma unroll
        for (int h = 0; h < 2; ++h) {  // K-half phases
            __syncthreads();  // previous phase's readers done before overwrite
            #pragma unroll
            for (int r = 0; r < 4; ++r) {
                int srcoff = (r * 32 + srow) * 256 + h * 128 + g * 16;
                int dstoff = r * 4096 + dstb;
                async_copy16(xg + srcoff, (char*)xs + dstoff);
                async_copy16(yg + srcoff, (char*)ys + dstoff);
            }
            __syncthreads();  // tiles ready (drains vmcnt)

            #pragma unroll
            for (int kk = 0; kk < 2; ++kk) {
                const int cb = kk << 2;
                const int sw = ((cb | quad) ^ (l15 & 7)) << 3;  // f16 offset
                f16x8 a[4], bf[4];
                #pragma unroll
                for (int fi = 0; fi < 4; ++fi)
                    a[fi] = *(const f16x8*)&xs[(wr * 64 + fi * 16 + l15) * 64 + sw];
                #pragma unroll
                for (int fj = 0; fj < 4; ++fj)
                    bf[fj] = *(const f16x8*)&ys[(wc * 64 + fj * 16 + l15) * 64 + sw];
                #pragma unroll
                for (int fi = 0; fi < 4; ++fi)
                    #pragma unroll
                    for (int fj = 0; fj < 4; ++fj)
                        acc[fi][fj] = __builtin_amdgcn_mfma_f32_16x16x32_f16(
                            a[fi], bf[fj], acc[fi][fj], 0, 0, 0);
            }
        }

        // epilogue per batch on SQUARED distances (sqrt deferred)
        float y2v[4];
        #pragma unroll
        for (int fj = 0; fj < 4; ++fj)
            y2v[fj] = y2s[b][wc * 64 + fj * 16 + l15];

        float fwd_min[4] = {INF, INF, INF, INF};
        #pragma unroll
        for (int fi = 0; fi < 4; ++fi) {
            const f32x4 x2v = *(const f32x4*)&x2s[b][wr * 64 + fi * 16 + quad * 4];
            #pragma unroll
            for (int fj = 0; fj < 4; ++fj) {
                #pragma unroll
                for (int e = 0; e < 4; ++e) {
                    float sqv = fmaf(-2.0f, acc[fi][fj][e], x2v[e] + y2v[fj]);
                    bmin[fi][fj][e] = fminf(bmin[fi][fj][e], sqv);
                    fwd_min[fj]     = fminf(fwd_min[fj], sqv);
                }
            }
        }
        #pragma unroll
        for (int fj = 0; fj < 4; ++fj) {
            float v = fwd_min[fj];
            v = fminf(v, __shfl_xor(v, 16, 64));
            v = fminf(v, __shfl_xor(v, 32, 64));
            if (quad == 0)
                fbuf[wr][b][wc * 64 + fj * 16 + l15] = v;  // one write per slot
        }
    }
    __syncthreads();  // fbuf complete

    // forward: combine wr halves, clamp, one atomicMin per (b,col)
    for (int i = tid; i < BB * 128; i += 256) {
        int b = i >> 7, c = i & 127;
        float v = fminf(fbuf[0][b][c], fbuf[1][b][c]);
        v = fmaxf(v, 0.0f);  // clamp so uint ordering == float ordering
        atomicMin(&fwd[(size_t)b * MM + m0 + c], __float_as_uint(v));
    }

    // backward: sqrt(clamp(min-over-b)), sum, one atomicAdd per wave
    float s = 0.0f;
    #pragma unroll
    for (int fi = 0; fi < 4; ++fi)
        #pragma unroll
        for (int fj = 0; fj < 4; ++fj)
            #pragma unroll
            for (int e = 0; e < 4; ++e)
                s += sqrtf(fmaxf(bmin[fi][fj][e], 0.0f));
    #pragma unroll
    for (int off = 32; off; off >>= 1) s += __shfl_down(s, off, 64);
    if (lane == 0) atomicAdd(bsum, s);

    // fused finalize: last block reduces fwd + combines means
    __threadfence();
    if (tid == 0) {
        unsigned int c = atomicAdd(counter, 1u);
        isLast = (c == gridDim.x * gridDim.y - 1) ? 1 : 0;
    }
    __syncthreads();
    if (isLast) {
        float fs = 0.0f;
        for (int i = tid; i < BB * MM; i += 256) {
            unsigned int u = __hip_atomic_load(&fwd[i], __ATOMIC_RELAXED,
                                               __HIP_MEMORY_SCOPE_AGENT);
            fs += sqrtf(__uint_as_float(u));
        }
        #pragma unroll
        for (int off = 32; off; off >>= 1) fs += __shfl_down(fs, off, 64);
        if (lane == 0) red[wave] = fs;
        __syncthreads();
        if (tid == 0) {
            float ftot = red[0] + red[1] + red[2] + red[3];
            float bs = __hip_atomic_load(bsum, __ATOMIC_RELAXED,
                                         __HIP_MEMORY_SCOPE_AGENT);
            out[0] = ftot / (float)(BB * MM) + bs / ((float)NN * (float)MM);
        }
    }
}

extern "C" void kernel_launch(void* const* d_in, const int* in_sizes, int n_in,
                              void* d_out, int out_size, void* d_ws, size_t ws_size,
                              hipStream_t stream) {
    const float* x = (const float*)d_in[0];  // (B,N,D)
    const float* y = (const float*)d_in[1];  // (B,M,D)
    float* out = (float*)d_out;

    char* w = (char*)d_ws;
    _Float16* xh = (_Float16*)(w);                         // 8 MB
    _Float16* yh = (_Float16*)(w + 8388608);               // 8 MB
    float*    x2 = (float*)(w + 16777216);                 // 128 KB
    float*    y2 = (float*)(w + 16908288);                 // 128 KB
    unsigned int* fwd = (unsigned int*)(w + 17039360);     // 128 KB
    float*    bsum = (float*)(w + 17170432);               // 4 B
    unsigned int* counter = (unsigned int*)(w + 17170436); // 4 B

    prep_all<<<(2 * BB * NN) / 4, 256, 0, stream>>>(x, y, xh, yh, x2, y2,
                                                    fwd, bsum, counter);
    dim3 grid(NN / 128, MM / 128);
    chamfer_main<<<grid, 256, 0, stream>>>(xh, yh, x2, y2, fwd, bsum, counter, out);
}

// Round 5
// 249.506 us; speedup vs baseline: 1.7716x; 1.7716x over previous
//
#include <hip/hip_runtime.h>
#include <hip/hip_bf16.h>

#define BB 8
#define NN 4096
#define MM 4096
#define DD 128

typedef float  f32x4 __attribute__((ext_vector_type(4)));
typedef _Float16 f16x8 __attribute__((ext_vector_type(8)));
typedef _Float16 f16x4 __attribute__((ext_vector_type(4)));

__device__ __forceinline__ void async_copy16(const void* g, void* l) {
    __builtin_amdgcn_global_load_lds(
        (const __attribute__((address_space(1))) void*)g,
        (__attribute__((address_space(3))) void*)l, 16, 0, 0);
}

// Prep: fp32->f16 convert + exact fp32 squared row norms (both inputs) +
// init fwd/bsum/counter. float4 per lane; one row per 32-lane half-wave.
__global__ void prep_all(const float* __restrict__ x, const float* __restrict__ y,
                         _Float16* __restrict__ xh, _Float16* __restrict__ yh,
                         float* __restrict__ x2, float* __restrict__ y2,
                         unsigned int* __restrict__ fwd, float* __restrict__ bsum,
                         unsigned int* __restrict__ counter) {
    int gtid = blockIdx.x * blockDim.x + threadIdx.x;
    if (gtid < BB * MM) fwd[gtid] = 0x7f800000u;  // +inf bits
    if (gtid == 0) { *bsum = 0.0f; *counter = 0u; }

    int row = gtid >> 5;          // one row per 32 lanes
    int l32 = gtid & 31;
    const float* src;
    _Float16* dst;
    float* sq;
    if (row < BB * NN) {
        src = x; dst = xh; sq = x2;
    } else {
        src = y; dst = yh; sq = y2; row -= BB * NN;
    }
    f32x4 v = ((const f32x4*)src)[(size_t)row * 32 + l32];
    float s = v.x * v.x + v.y * v.y + v.z * v.z + v.w * v.w;
    ((f16x4*)dst)[(size_t)row * 32 + l32] = __builtin_convertvector(v, f16x4);
    #pragma unroll
    for (int m = 16; m; m >>= 1) s += __shfl_xor(s, m, 64);  // masks<32: stays in half
    if (l32 == 0) sq[row] = s;
}

// Main kernel: 128x128 tile, K-half double-buffered pipeline.
// Phase = one K-half (32KB staged): issue prefetch of NEXT half, compute
// CURRENT half, barrier (vmcnt drain covered by compute). One barrier/phase.
// LDS ~74KB -> 2 blocks/CU; b-loop rolled so VGPR stays under the 2-wave cap.
// XCD patch swizzle (id&7 -> 16x8 block patch) keeps per-batch working set
// (~768KB) inside one XCD's 4MB L2.
__global__ __launch_bounds__(256, 2)
void chamfer_main(const _Float16* __restrict__ xh, const _Float16* __restrict__ yh,
                  const float* __restrict__ x2, const float* __restrict__ y2,
                  unsigned int* __restrict__ fwd, float* __restrict__ bsum,
                  unsigned int* __restrict__ counter, float* __restrict__ out) {
    __shared__ _Float16 xs[2][128 * 64];  // 2 x 16 KB (K-half buffers)
    __shared__ _Float16 ys[2][128 * 64];  // 2 x 16 KB
    __shared__ float x2s[BB][128];        // 4 KB
    __shared__ float y2s[BB][128];        // 4 KB
    __shared__ float fbuf[2][128];        // 1 KB (per-batch fwd mins, wr halves)
    __shared__ float red[4];
    __shared__ int isLast;

    const int tid  = threadIdx.x;
    const int lane = tid & 63;
    const int wave = tid >> 6;
    const int wr   = wave >> 1;
    const int wc   = wave & 1;
    const int quad = lane >> 4;
    const int l15  = lane & 15;

    // XCD patch swizzle: xcd = id&7 (HW round-robin); patch = 16(bx) x 8(by)
    const int id  = blockIdx.x;
    const int xcd = id & 7;
    const int j   = id >> 3;
    const int bx  = ((xcd & 1) << 4) | (j & 15);
    const int by  = ((xcd >> 1) << 3) | (j >> 4);
    const int n0  = bx * 128;
    const int m0  = by * 128;

    // staging constants: per round r, row = r*32 + wave*8 + (lane>>3);
    // LDS chunk = lane&7, global chunk g = (lane&7) ^ (row&7) (row&7 == lane>>3)
    const int srow = wave * 8 + (lane >> 3);
    const int g    = (lane & 7) ^ (lane >> 3);
    const int dstb = wave * 1024 + lane * 16;

    auto stage = [&](const char* xg, const char* yg, int hoff,
                     _Float16* bxs, _Float16* bys) {
        #pragma unroll
        for (int r = 0; r < 4; ++r) {
            int srcoff = (r * 32 + srow) * 256 + hoff + g * 16;
            int dstoff = r * 4096 + dstb;
            async_copy16(xg + srcoff, (char*)bxs + dstoff);
            async_copy16(yg + srcoff, (char*)bys + dstoff);
        }
    };
    auto compute = [&](const _Float16* bxs, const _Float16* bys, f32x4 (&acc)[4][4]) {
        #pragma unroll
        for (int kk = 0; kk < 2; ++kk) {
            const int sw = (((kk << 2) | quad) ^ (l15 & 7)) << 3;  // f16 offset
            f16x8 a[4], bf[4];
            #pragma unroll
            for (int fi = 0; fi < 4; ++fi)
                a[fi] = *(const f16x8*)&bxs[(wr * 64 + fi * 16 + l15) * 64 + sw];
            #pragma unroll
            for (int fj = 0; fj < 4; ++fj)
                bf[fj] = *(const f16x8*)&bys[(wc * 64 + fj * 16 + l15) * 64 + sw];
            #pragma unroll
            for (int fi = 0; fi < 4; ++fi)
                #pragma unroll
                for (int fj = 0; fj < 4; ++fj)
                    acc[fi][fj] = __builtin_amdgcn_mfma_f32_16x16x32_f16(
                        a[fi], bf[fj], acc[fi][fj], 0, 0, 0);
        }
    };
    auto readback = [&](int bb) {  // fbuf -> global atomicMin (drain-covered)
        if (tid < 128) {
            float v = fminf(fbuf[0][tid], fbuf[1][tid]);
            v = fmaxf(v, 0.0f);  // clamp so uint ordering == float ordering
            atomicMin(&fwd[(size_t)bb * MM + m0 + tid], __float_as_uint(v));
        }
    };

    // stage x2/y2 slices for all batches
    for (int i = tid; i < BB * 128; i += 256) {
        int b = i >> 7, c = i & 127;
        x2s[b][c] = x2[(size_t)b * NN + n0 + c];
        y2s[b][c] = y2[(size_t)b * MM + m0 + c];
    }

    const float INF = __builtin_inff();
    f32x4 bmin[4][4];
    #pragma unroll
    for (int i = 0; i < 4; ++i)
        #pragma unroll
        for (int j2 = 0; j2 < 4; ++j2)
            bmin[i][j2] = (f32x4){INF, INF, INF, INF};

    // prologue: stage batch 0, K-half 0 into buffer 0
    {
        const char* xg = (const char*)(xh + ((size_t)0 * NN + n0) * DD);
        const char* yg = (const char*)(yh + ((size_t)0 * MM + m0) * DD);
        stage(xg, yg, 0, xs[0], ys[0]);
    }
    __syncthreads();

    #pragma unroll 1
    for (int b = 0; b < BB; ++b) {
        const char* xg = (const char*)(xh + ((size_t)b * NN + n0) * DD);
        const char* yg = (const char*)(yh + ((size_t)b * MM + m0) * DD);

        f32x4 acc[4][4];
        #pragma unroll
        for (int i = 0; i < 4; ++i)
            #pragma unroll
            for (int j2 = 0; j2 < 4; ++j2)
                acc[i][j2] = (f32x4){0.f, 0.f, 0.f, 0.f};

        // ---- phase h=0: prefetch h=1 -> buf1; compute buf0 ----
        stage(xg, yg, 128, xs[1], ys[1]);
        if (b > 0) readback(b - 1);
        compute(xs[0], ys[0], acc);
        __syncthreads();  // drains h=1 prefetch (covered by compute above)

        // ---- phase h=1: prefetch next batch h=0 -> buf0; compute buf1 ----
        if (b < BB - 1) {
            const char* xgn = (const char*)(xh + ((size_t)(b + 1) * NN + n0) * DD);
            const char* ygn = (const char*)(yh + ((size_t)(b + 1) * MM + m0) * DD);
            stage(xgn, ygn, 0, xs[0], ys[0]);
        }
        compute(xs[1], ys[1], acc);

        // epilogue on SQUARED distances (sqrt deferred; min is monotone)
        float y2v[4];
        #pragma unroll
        for (int fj = 0; fj < 4; ++fj)
            y2v[fj] = y2s[b][wc * 64 + fj * 16 + l15];

        float fwd_min[4] = {INF, INF, INF, INF};
        #pragma unroll
        for (int fi = 0; fi < 4; ++fi) {
            const f32x4 x2v = *(const f32x4*)&x2s[b][wr * 64 + fi * 16 + quad * 4];
            #pragma unroll
            for (int fj = 0; fj < 4; ++fj) {
                #pragma unroll
                for (int e = 0; e < 4; ++e) {
                    float sqv = fmaf(-2.0f, acc[fi][fj][e], x2v[e] + y2v[fj]);
                    bmin[fi][fj][e] = fminf(bmin[fi][fj][e], sqv);
                    fwd_min[fj]     = fminf(fwd_min[fj], sqv);
                }
            }
        }
        #pragma unroll
        for (int fj = 0; fj < 4; ++fj) {
            float v = fwd_min[fj];
            v = fminf(v, __shfl_xor(v, 16, 64));
            v = fminf(v, __shfl_xor(v, 32, 64));
            if (quad == 0)
                fbuf[wr][wc * 64 + fj * 16 + l15] = v;  // one write per slot
        }
        __syncthreads();  // drains next-batch prefetch + publishes fbuf
    }
    readback(BB - 1);

    // backward: sqrt(clamp(min-over-b)), sum, one atomicAdd per wave
    float s = 0.0f;
    #pragma unroll
    for (int fi = 0; fi < 4; ++fi)
        #pragma unroll
        for (int fj = 0; fj < 4; ++fj)
            #pragma unroll
            for (int e = 0; e < 4; ++e)
                s += sqrtf(fmaxf(bmin[fi][fj][e], 0.0f));
    #pragma unroll
    for (int off = 32; off; off >>= 1) s += __shfl_down(s, off, 64);
    if (lane == 0) atomicAdd(bsum, s);

    // fused finalize: last block reduces fwd + combines means
    __threadfence();
    __syncthreads();  // all threads' global ops fenced before counter bump
    if (tid == 0) {
        unsigned int c = atomicAdd(counter, 1u);
        isLast = (c == gridDim.x - 1) ? 1 : 0;
    }
    __syncthreads();
    if (isLast) {
        __threadfence();
        float fs = 0.0f;
        for (int i = tid; i < BB * MM; i += 256) {
            unsigned int u = __hip_atomic_load(&fwd[i], __ATOMIC_RELAXED,
                                               __HIP_MEMORY_SCOPE_AGENT);
            fs += sqrtf(__uint_as_float(u));
        }
        #pragma unroll
        for (int off = 32; off; off >>= 1) fs += __shfl_down(fs, off, 64);
        if (lane == 0) red[wave] = fs;
        __syncthreads();
        if (tid == 0) {
            float ftot = red[0] + red[1] + red[2] + red[3];
            float bs = __hip_atomic_load(bsum, __ATOMIC_RELAXED,
                                         __HIP_MEMORY_SCOPE_AGENT);
            out[0] = ftot / (float)(BB * MM) + bs / ((float)NN * (float)MM);
        }
    }
}

extern "C" void kernel_launch(void* const* d_in, const int* in_sizes, int n_in,
                              void* d_out, int out_size, void* d_ws, size_t ws_size,
                              hipStream_t stream) {
    const float* x = (const float*)d_in[0];  // (B,N,D)
    const float* y = (const float*)d_in[1];  // (B,M,D)
    float* out = (float*)d_out;

    char* w = (char*)d_ws;
    _Float16* xh = (_Float16*)(w);                         // 8 MB
    _Float16* yh = (_Float16*)(w + 8388608);               // 8 MB
    float*    x2 = (float*)(w + 16777216);                 // 128 KB
    float*    y2 = (float*)(w + 16908288);                 // 128 KB
    unsigned int* fwd = (unsigned int*)(w + 17039360);     // 128 KB
    float*    bsum = (float*)(w + 17170432);               // 4 B
    unsigned int* counter = (unsigned int*)(w + 17170436); // 4 B

    // 65536 rows, one per 32 lanes -> 2M threads
    prep_all<<<(2 * BB * NN * 32) / 256, 256, 0, stream>>>(x, y, xh, yh, x2, y2,
                                                           fwd, bsum, counter);
    chamfer_main<<<1024, 256, 0, stream>>>(xh, yh, x2, y2, fwd, bsum, counter, out);
}

// Round 6
// 209.889 us; speedup vs baseline: 2.1060x; 1.1888x over previous
//
#include <hip/hip_runtime.h>
#include <hip/hip_fp8.h>

#define BB 8
#define NN 4096
#define MM 4096
#define DD 128

typedef float f32x4 __attribute__((ext_vector_type(4)));

__device__ __forceinline__ void async_copy16(const void* g, void* l) {
    __builtin_amdgcn_global_load_lds(
        (const __attribute__((address_space(1))) void*)g,
        (__attribute__((address_space(3))) void*)l, 16, 0, 0);
}

// Prep: fp32 -> fp8 e4m3 convert + EXACT fp32 squared row norms (gram trick
// keeps norms exact; only the cross term is fp8). One row per 32-lane half.
__global__ void prep_all(const float* __restrict__ x, const float* __restrict__ y,
                         unsigned char* __restrict__ xq, unsigned char* __restrict__ yq,
                         float* __restrict__ x2, float* __restrict__ y2,
                         unsigned int* __restrict__ fwd, float* __restrict__ bsum,
                         unsigned int* __restrict__ counter) {
    int gtid = blockIdx.x * blockDim.x + threadIdx.x;
    if (gtid < BB * MM) fwd[gtid] = 0x7f800000u;  // +inf bits
    if (gtid == 0) { *bsum = 0.0f; *counter = 0u; }

    int row = gtid >> 5;
    int l32 = gtid & 31;
    const float* src;
    unsigned char* dst;
    float* sq;
    if (row < BB * NN) {
        src = x; dst = xq; sq = x2;
    } else {
        src = y; dst = yq; sq = y2; row -= BB * NN;
    }
    f32x4 v = ((const f32x4*)src)[(size_t)row * 32 + l32];
    float s = v.x * v.x + v.y * v.y + v.z * v.z + v.w * v.w;
    unsigned int p;
    p  = (unsigned int)__hip_cvt_float_to_fp8(v.x, __HIP_SATFINITE, __HIP_E4M3);
    p |= (unsigned int)__hip_cvt_float_to_fp8(v.y, __HIP_SATFINITE, __HIP_E4M3) << 8;
    p |= (unsigned int)__hip_cvt_float_to_fp8(v.z, __HIP_SATFINITE, __HIP_E4M3) << 16;
    p |= (unsigned int)__hip_cvt_float_to_fp8(v.w, __HIP_SATFINITE, __HIP_E4M3) << 24;
    ((unsigned int*)dst)[(size_t)row * 32 + l32] = p;
    #pragma unroll
    for (int m = 16; m; m >>= 1) s += __shfl_xor(s, m, 64);  // stays in 32-half
    if (l32 == 0) sq[row] = s;
}

// Main: 128x128 tile, fp8 tiles (16 KB each) -> FULL batch per phase,
// double-buffered: prefetch batch b+1, compute batch b, ONE barrier/batch.
// Zero global ops inside the loop (fwd mins -> LDS fbuf atomicMin).
// XOR swizzle on 8B granules (g ^= (row>>1)&7): staging stays clean 16B
// chunk copies; ds_read_b64 is 2-way (free). LDS ~76KB -> 2 blocks/CU.
__global__ __launch_bounds__(256, 2)
void chamfer_main(const unsigned char* __restrict__ xq, const unsigned char* __restrict__ yq,
                  const float* __restrict__ x2, const float* __restrict__ y2,
                  unsigned int* __restrict__ fwd, float* __restrict__ bsum,
                  unsigned int* __restrict__ counter, float* __restrict__ out) {
    __shared__ unsigned char xs[2][128 * 128];  // 2 x 16 KB
    __shared__ unsigned char ys[2][128 * 128];  // 2 x 16 KB
    __shared__ float x2s[BB][128];              // 4 KB
    __shared__ float y2s[BB][128];              // 4 KB
    __shared__ float fbuf[BB][128];             // 4 KB (fwd min per (b,col))
    __shared__ float red[4];
    __shared__ int isLast;

    const int tid  = threadIdx.x;
    const int lane = tid & 63;
    const int wave = tid >> 6;
    const int wr   = wave >> 1;
    const int wc   = wave & 1;
    const int quad = lane >> 4;
    const int l15  = lane & 15;

    // XCD patch swizzle: xcd = id&7; patch = 16(bx) x 8(by) tiles per XCD
    const int id  = blockIdx.x;
    const int xcd = id & 7;
    const int j   = id >> 3;
    const int bx  = ((xcd & 1) << 4) | (j & 15);
    const int by  = ((xcd >> 1) << 3) | (j >> 4);
    const int n0  = bx * 128;
    const int m0  = by * 128;

    // staging: instr r covers rows r*32 + wave*8 + (lane>>3) (128B fp8 rows);
    // dst chunk c = lane&7 holds global chunk c ^ ((row>>1)&7)
    const int srow   = wave * 8 + (lane >> 3);
    const int schunk = (lane & 7) ^ ((wave * 4 + ((lane >> 3) >> 1)) & 7);
    const int dstb   = wave * 1024 + lane * 16;

    auto stage = [&](const unsigned char* gx, const unsigned char* gy,
                     unsigned char* bxs, unsigned char* bys) {
        #pragma unroll
        for (int r = 0; r < 4; ++r) {
            int srcoff = (r * 32 + srow) * 128 + schunk * 16;
            int dstoff = r * 4096 + dstb;
            async_copy16(gx + srcoff, bxs + dstoff);
            async_copy16(gy + srcoff, bys + dstoff);
        }
    };
    // swizzled ds_read_b64 address for fragment row, k-step kk, this lane:
    // granule g = kk*2 + (quad>>1) (8B pairs), XOR (row>>1)&7 == l15>>1
    auto frag_off = [&](int rowbase, int kk) {
        int gb = ((kk * 2 + (quad >> 1)) ^ (l15 >> 1));
        return (rowbase + l15) * 128 + ((gb << 1) | (quad & 1)) * 8;
    };

    // one-time: norms + fbuf init
    for (int i = tid; i < BB * 128; i += 256) {
        int b = i >> 7, c = i & 127;
        x2s[b][c] = x2[(size_t)b * NN + n0 + c];
        y2s[b][c] = y2[(size_t)b * MM + m0 + c];
        fbuf[b][c] = __builtin_inff();
    }

    // prologue: stage batch 0 into buffer 0
    stage(xq + ((size_t)0 * NN + n0) * DD, yq + ((size_t)0 * MM + m0) * DD,
          xs[0], ys[0]);
    __syncthreads();

    const float INF = __builtin_inff();
    f32x4 bmin[4][4];
    #pragma unroll
    for (int i = 0; i < 4; ++i)
        #pragma unroll
        for (int j2 = 0; j2 < 4; ++j2)
            bmin[i][j2] = (f32x4){INF, INF, INF, INF};

    #pragma unroll 1
    for (int b = 0; b < BB; ++b) {
        const int cur = b & 1;
        const int nxt = cur ^ 1;

        // prefetch next batch (covered by this batch's compute)
        if (b < BB - 1) {
            stage(xq + ((size_t)(b + 1) * NN + n0) * DD,
                  yq + ((size_t)(b + 1) * MM + m0) * DD, xs[nxt], ys[nxt]);
        }

        f32x4 acc[4][4];
        #pragma unroll
        for (int i = 0; i < 4; ++i)
            #pragma unroll
            for (int j2 = 0; j2 < 4; ++j2)
                acc[i][j2] = (f32x4){0.f, 0.f, 0.f, 0.f};

        const unsigned char* bxs = xs[cur];
        const unsigned char* bys = ys[cur];
        #pragma unroll
        for (int kk = 0; kk < 4; ++kk) {
            long a[4], bf[4];
            #pragma unroll
            for (int fi = 0; fi < 4; ++fi)
                a[fi] = *(const long*)&bxs[frag_off(wr * 64 + fi * 16, kk)];
            #pragma unroll
            for (int fj = 0; fj < 4; ++fj)
                bf[fj] = *(const long*)&bys[frag_off(wc * 64 + fj * 16, kk)];
            #pragma unroll
            for (int fi = 0; fi < 4; ++fi)
                #pragma unroll
                for (int fj = 0; fj < 4; ++fj)
                    acc[fi][fj] = __builtin_amdgcn_mfma_f32_16x16x32_fp8_fp8(
                        a[fi], bf[fj], acc[fi][fj], 0, 0, 0);
        }

        // epilogue on SQUARED distances (sqrt deferred; min is monotone)
        float y2v[4];
        #pragma unroll
        for (int fj = 0; fj < 4; ++fj)
            y2v[fj] = y2s[b][wc * 64 + fj * 16 + l15];

        float fwd_min[4] = {INF, INF, INF, INF};
        #pragma unroll
        for (int fi = 0; fi < 4; ++fi) {
            const f32x4 x2v = *(const f32x4*)&x2s[b][wr * 64 + fi * 16 + quad * 4];
            #pragma unroll
            for (int fj = 0; fj < 4; ++fj) {
                #pragma unroll
                for (int e = 0; e < 4; ++e) {
                    float sqv = fmaf(-2.0f, acc[fi][fj][e], x2v[e] + y2v[fj]);
                    bmin[fi][fj][e] = fminf(bmin[fi][fj][e], sqv);
                    fwd_min[fj]     = fminf(fwd_min[fj], sqv);
                }
            }
        }
        #pragma unroll
        for (int fj = 0; fj < 4; ++fj) {
            float v = fwd_min[fj];
            v = fminf(v, __shfl_xor(v, 16, 64));
            v = fminf(v, __shfl_xor(v, 32, 64));
            v = fmaxf(v, 0.0f);  // clamp: uint ordering == float ordering
            if (quad == 0)
                atomicMin((unsigned int*)&fbuf[b][wc * 64 + fj * 16 + l15],
                          __float_as_uint(v));
        }
        __syncthreads();  // drains prefetch + fbuf atomics; guards buffer swap
    }

    // forward readback: one global atomicMin per (b,col), once per block
    for (int i = tid; i < BB * 128; i += 256) {
        int b = i >> 7, c = i & 127;
        atomicMin(&fwd[(size_t)b * MM + m0 + c],
                  __float_as_uint(fbuf[b][c]));
    }

    // backward: sqrt(clamp(min-over-b)), sum, one atomicAdd per wave
    float s = 0.0f;
    #pragma unroll
    for (int fi = 0; fi < 4; ++fi)
        #pragma unroll
        for (int fj = 0; fj < 4; ++fj)
            #pragma unroll
            for (int e = 0; e < 4; ++e)
                s += sqrtf(fmaxf(bmin[fi][fj][e], 0.0f));
    #pragma unroll
    for (int off = 32; off; off >>= 1) s += __shfl_down(s, off, 64);
    if (lane == 0) atomicAdd(bsum, s);

    // fused finalize: last block reduces fwd + combines means
    __threadfence();
    __syncthreads();
    if (tid == 0) {
        unsigned int c = atomicAdd(counter, 1u);
        isLast = (c == gridDim.x - 1) ? 1 : 0;
    }
    __syncthreads();
    if (isLast) {
        __threadfence();
        float fs = 0.0f;
        const uint4* fw4 = (const uint4*)fwd;
        for (int i = tid; i < (BB * MM) / 4; i += 256) {
            uint4 u = fw4[i];
            fs += sqrtf(__uint_as_float(u.x)) + sqrtf(__uint_as_float(u.y)) +
                  sqrtf(__uint_as_float(u.z)) + sqrtf(__uint_as_float(u.w));
        }
        #pragma unroll
        for (int off = 32; off; off >>= 1) fs += __shfl_down(fs, off, 64);
        if (lane == 0) red[wave] = fs;
        __syncthreads();
        if (tid == 0) {
            float ftot = red[0] + red[1] + red[2] + red[3];
            float bs = __hip_atomic_load(bsum, __ATOMIC_RELAXED,
                                         __HIP_MEMORY_SCOPE_AGENT);
            out[0] = ftot / (float)(BB * MM) + bs / ((float)NN * (float)MM);
        }
    }
}

extern "C" void kernel_launch(void* const* d_in, const int* in_sizes, int n_in,
                              void* d_out, int out_size, void* d_ws, size_t ws_size,
                              hipStream_t stream) {
    const float* x = (const float*)d_in[0];  // (B,N,D)
    const float* y = (const float*)d_in[1];  // (B,M,D)
    float* out = (float*)d_out;

    char* w = (char*)d_ws;
    unsigned char* xq = (unsigned char*)(w);               // 4 MB fp8
    unsigned char* yq = (unsigned char*)(w + 4194304);     // 4 MB fp8
    float*    x2 = (float*)(w + 8388608);                  // 128 KB
    float*    y2 = (float*)(w + 8519680);                  // 128 KB
    unsigned int* fwd = (unsigned int*)(w + 8650752);      // 128 KB
    float*    bsum = (float*)(w + 8781824);                // 4 B
    unsigned int* counter = (unsigned int*)(w + 8781828);  // 4 B

    // 65536 rows, one per 32 lanes
    prep_all<<<(2 * BB * NN * 32) / 256, 256, 0, stream>>>(x, y, xq, yq, x2, y2,
                                                           fwd, bsum, counter);
    chamfer_main<<<1024, 256, 0, stream>>>(xq, yq, x2, y2, fwd, bsum, counter, out);
}

// Round 7
// 209.123 us; speedup vs baseline: 2.1138x; 1.0037x over previous
//
#include <hip/hip_runtime.h>
#include <hip/hip_fp8.h>

#define BB 8
#define NN 4096
#define MM 4096
#define DD 128

typedef float f32x4 __attribute__((ext_vector_type(4)));
typedef long  long2v __attribute__((ext_vector_type(2)));

// ---------------------------------------------------------------------------
// Prep: fp32 -> fp8 e4m3, written in MFMA-FRAGMENT ORDER, + exact fp32 row
// norms (gram trick: only the cross term is fp8). Fragment layout for
// mfma_f32_16x16x32_fp8_fp8 (HW-verified in round 6): lane(l15,quad) holds
// row=l15, k=quad*8..+8. Packed so one dwordx4 per lane covers K-pair
// (kk=2h, 2h+1):  byte = ((g*2 + h)*1024) + (quad*16 + (row&15))*16 + p*8 + (k&7)
// where g = row>>4, kk = k>>5, h = kk>>1, p = kk&1.
// One row per 32-lane half-wave; each thread converts 4 floats.
// ---------------------------------------------------------------------------
__global__ void prep_all(const float* __restrict__ x, const float* __restrict__ y,
                         unsigned char* __restrict__ xq, unsigned char* __restrict__ yq,
                         float* __restrict__ x2, float* __restrict__ y2,
                         unsigned int* __restrict__ fwd, float* __restrict__ bsum,
                         unsigned int* __restrict__ counter) {
    int gtid = blockIdx.x * blockDim.x + threadIdx.x;
    if (gtid < BB * MM) fwd[gtid] = 0x7f800000u;  // +inf bits
    if (gtid == 0) { *bsum = 0.0f; *counter = 0u; }

    int row = gtid >> 5;
    int k4  = gtid & 31;
    const float* src;
    unsigned char* dst;
    float* sq;
    if (row < BB * NN) {
        src = x; dst = xq; sq = x2;
    } else {
        src = y; dst = yq; sq = y2; row -= BB * NN;
    }
    f32x4 v = ((const f32x4*)src)[(size_t)row * 32 + k4];
    float s = v.x * v.x + v.y * v.y + v.z * v.z + v.w * v.w;
    unsigned int p32;
    p32  = (unsigned int)__hip_cvt_float_to_fp8(v.x, __HIP_SATFINITE, __HIP_E4M3);
    p32 |= (unsigned int)__hip_cvt_float_to_fp8(v.y, __HIP_SATFINITE, __HIP_E4M3) << 8;
    p32 |= (unsigned int)__hip_cvt_float_to_fp8(v.z, __HIP_SATFINITE, __HIP_E4M3) << 16;
    p32 |= (unsigned int)__hip_cvt_float_to_fp8(v.w, __HIP_SATFINITE, __HIP_E4M3) << 24;

    int k    = k4 << 2;
    int kk   = k >> 5;
    int h    = kk >> 1;
    int p    = kk & 1;
    int quad = (k >> 3) & 3;
    size_t dstoff = ((size_t)(row >> 4) * 2 + h) * 1024
                  + (size_t)(quad * 16 + (row & 15)) * 16 + p * 8 + (k & 7);
    *(unsigned int*)(dst + dstoff) = p32;

    #pragma unroll
    for (int m = 16; m; m >>= 1) s += __shfl_xor(s, m, 64);  // stays in 32-half
    if (k4 == 0) sq[row] = s;
}

// ---------------------------------------------------------------------------
// Main: NO LDS tiles, NO barriers in the b-loop. Each wave owns a 64x64
// (n,m) tile; fragments load straight global->VGPR as coalesced dwordx4
// from the fragment-ordered buffers. Block = 4 waves stacked in n (256x64)
// sharing the m-range; forward mins combine via LDS atomicMin (2KB).
// XCD swizzle: xcd = id&7 owns an m-stripe of 512 -> per-XCD per-batch
// working set (x 512KB + y 64KB) is L2-resident.
// ---------------------------------------------------------------------------
__global__ __launch_bounds__(256)
void chamfer_main(const unsigned char* __restrict__ xq, const unsigned char* __restrict__ yq,
                  const float* __restrict__ x2, const float* __restrict__ y2,
                  unsigned int* __restrict__ fwd, float* __restrict__ bsum,
                  unsigned int* __restrict__ counter, float* __restrict__ out) {
    __shared__ float fbuf[BB][64];  // 2 KB: fwd min per (b, col-in-block)
    __shared__ float red[4];
    __shared__ int isLast;

    const int tid  = threadIdx.x;
    const int lane = tid & 63;
    const int wave = tid >> 6;
    const int quad = lane >> 4;
    const int l15  = lane & 15;

    // id -> (nb 0..15, mb 0..63) with XCD m-stripe swizzle
    const int id  = blockIdx.x;
    const int xcd = id & 7;
    const int r   = id >> 3;
    const int nb  = r & 15;
    const int mb  = xcd * 8 + (r >> 4);
    const int n0w = nb * 256 + wave * 64;   // this wave's n-base
    const int m0  = mb * 64;                // block-shared m-base

    const int xg0 = n0w >> 4;  // x row-group base (within a batch)
    const int yg0 = m0 >> 4;
    const size_t lane16 = (size_t)lane * 16;

    // init fbuf, then the only pre-loop barrier
    for (int i = tid; i < BB * 64; i += 256)
        ((unsigned int*)fbuf)[i] = 0x7f800000u;
    __syncthreads();

    const float INF = __builtin_inff();
    f32x4 bmin[4][4];
    #pragma unroll
    for (int i = 0; i < 4; ++i)
        #pragma unroll
        for (int j = 0; j < 4; ++j)
            bmin[i][j] = (f32x4){INF, INF, INF, INF};

    #pragma unroll 1
    for (int b = 0; b < BB; ++b) {
        // fragment bases for this batch (256 row-groups per batch)
        const unsigned char* xb = xq + ((size_t)(b * 256 + xg0) * 2) * 1024;
        const unsigned char* yb = yq + ((size_t)(b * 256 + yg0) * 2) * 1024;

        f32x4 acc[4][4];
        #pragma unroll
        for (int i = 0; i < 4; ++i)
            #pragma unroll
            for (int j = 0; j < 4; ++j)
                acc[i][j] = (f32x4){0.f, 0.f, 0.f, 0.f};

        #pragma unroll
        for (int h = 0; h < 2; ++h) {
            long2v xv[4], yv[4];
            #pragma unroll
            for (int fi = 0; fi < 4; ++fi)
                xv[fi] = *(const long2v*)(xb + (((fi << 1) + h) << 10) + lane16);
            #pragma unroll
            for (int fj = 0; fj < 4; ++fj)
                yv[fj] = *(const long2v*)(yb + (((fj << 1) + h) << 10) + lane16);
            #pragma unroll
            for (int p = 0; p < 2; ++p)
                #pragma unroll
                for (int fi = 0; fi < 4; ++fi)
                    #pragma unroll
                    for (int fj = 0; fj < 4; ++fj)
                        acc[fi][fj] = __builtin_amdgcn_mfma_f32_16x16x32_fp8_fp8(
                            xv[fi][p], yv[fj][p], acc[fi][fj], 0, 0, 0);
        }

        // epilogue on SQUARED distances (sqrt deferred; min is monotone)
        float y2v[4];
        #pragma unroll
        for (int fj = 0; fj < 4; ++fj)
            y2v[fj] = y2[(size_t)b * MM + m0 + fj * 16 + l15];

        float fwd_min[4] = {INF, INF, INF, INF};
        #pragma unroll
        for (int fi = 0; fi < 4; ++fi) {
            const f32x4 x2v = *(const f32x4*)(x2 + (size_t)b * NN + n0w + fi * 16 + quad * 4);
            #pragma unroll
            for (int fj = 0; fj < 4; ++fj) {
                #pragma unroll
                for (int e = 0; e < 4; ++e) {
                    float sqv = fmaf(-2.0f, acc[fi][fj][e], x2v[e] + y2v[fj]);
                    bmin[fi][fj][e] = fminf(bmin[fi][fj][e], sqv);
                    fwd_min[fj]     = fminf(fwd_min[fj], sqv);
                }
            }
        }
        // reduce over the 4 quads (rows), then LDS atomicMin (no barrier needed)
        #pragma unroll
        for (int fj = 0; fj < 4; ++fj) {
            float v = fwd_min[fj];
            v = fminf(v, __shfl_xor(v, 16, 64));
            v = fminf(v, __shfl_xor(v, 32, 64));
            v = fmaxf(v, 0.0f);  // clamp: uint ordering == float ordering
            if (quad == 0)
                atomicMin((unsigned int*)&fbuf[b][fj * 16 + l15],
                          __float_as_uint(v));
        }
    }

    // backward: sqrt(clamp(min-over-b)), sum, one atomicAdd per wave
    float s = 0.0f;
    #pragma unroll
    for (int fi = 0; fi < 4; ++fi)
        #pragma unroll
        for (int fj = 0; fj < 4; ++fj)
            #pragma unroll
            for (int e = 0; e < 4; ++e)
                s += sqrtf(fmaxf(bmin[fi][fj][e], 0.0f));
    #pragma unroll
    for (int off = 32; off; off >>= 1) s += __shfl_down(s, off, 64);
    if (lane == 0) atomicAdd(bsum, s);

    // flush forward mins: one global atomicMin per (b, col)
    __syncthreads();  // all 4 waves' fbuf contributions visible
    for (int i = tid; i < BB * 64; i += 256) {
        int b = i >> 6, c = i & 63;
        atomicMin(&fwd[(size_t)b * MM + m0 + c], __float_as_uint(fbuf[b][c]));
    }

    // fused finalize: last block reduces fwd + combines means
    __threadfence();
    __syncthreads();
    if (tid == 0) {
        unsigned int c = atomicAdd(counter, 1u);
        isLast = (c == gridDim.x - 1) ? 1 : 0;
    }
    __syncthreads();
    if (isLast) {
        __threadfence();
        float fs = 0.0f;
        const uint4* fw4 = (const uint4*)fwd;
        for (int i = tid; i < (BB * MM) / 4; i += 256) {
            uint4 u = fw4[i];
            fs += sqrtf(__uint_as_float(u.x)) + sqrtf(__uint_as_float(u.y)) +
                  sqrtf(__uint_as_float(u.z)) + sqrtf(__uint_as_float(u.w));
        }
        #pragma unroll
        for (int off = 32; off; off >>= 1) fs += __shfl_down(fs, off, 64);
        if (lane == 0) red[wave] = fs;
        __syncthreads();
        if (tid == 0) {
            float ftot = red[0] + red[1] + red[2] + red[3];
            float bs = __hip_atomic_load(bsum, __ATOMIC_RELAXED,
                                         __HIP_MEMORY_SCOPE_AGENT);
            out[0] = ftot / (float)(BB * MM) + bs / ((float)NN * (float)MM);
        }
    }
}

extern "C" void kernel_launch(void* const* d_in, const int* in_sizes, int n_in,
                              void* d_out, int out_size, void* d_ws, size_t ws_size,
                              hipStream_t stream) {
    const float* x = (const float*)d_in[0];  // (B,N,D)
    const float* y = (const float*)d_in[1];  // (B,M,D)
    float* out = (float*)d_out;

    char* w = (char*)d_ws;
    unsigned char* xq = (unsigned char*)(w);               // 4 MB fp8 (frag order)
    unsigned char* yq = (unsigned char*)(w + 4194304);     // 4 MB fp8 (frag order)
    float*    x2 = (float*)(w + 8388608);                  // 128 KB
    float*    y2 = (float*)(w + 8519680);                  // 128 KB
    unsigned int* fwd = (unsigned int*)(w + 8650752);      // 128 KB
    float*    bsum = (float*)(w + 8781824);                // 4 B
    unsigned int* counter = (unsigned int*)(w + 8781828);  // 4 B

    // 65536 rows, one per 32 lanes
    prep_all<<<(2 * BB * NN * 32) / 256, 256, 0, stream>>>(x, y, xq, yq, x2, y2,
                                                           fwd, bsum, counter);
    chamfer_main<<<1024, 256, 0, stream>>>(xq, yq, x2, y2, fwd, bsum, counter, out);
}

// Round 8
// 198.068 us; speedup vs baseline: 2.2317x; 1.0558x over previous
//
#include <hip/hip_runtime.h>
#include <hip/hip_fp8.h>

#define BB 8
#define NN 4096
#define MM 4096
#define DD 128

typedef float f32x4 __attribute__((ext_vector_type(4)));
typedef long  long2v __attribute__((ext_vector_type(2)));

// ---------------------------------------------------------------------------
// Fragment-ordered fp8 layout (verified R7, absmax 0): for 16-row group g,
// K-half h, the 1KB unit holds lane(quad,l15) -> 16B: row=l15 (within group),
// k=(2h+p)*32+quad*8+(0..7) at byte p*8+(k&7).
// ---------------------------------------------------------------------------

// Prep v2: one 16-row group per 512-thread block. Coalesced float4 reads +
// exact fp32 norms (32-lane shfl), fp8 via LDS (padded stride 34 -> ~2-way),
// then fully-coalesced 16B fragment-ordered stores.
__global__ __launch_bounds__(512)
void prep_all(const float* __restrict__ x, const float* __restrict__ y,
              unsigned char* __restrict__ xq, unsigned char* __restrict__ yq,
              float* __restrict__ x2, float* __restrict__ y2,
              unsigned int* __restrict__ fwd, float* __restrict__ bsum,
              float* __restrict__ fsum, unsigned int* __restrict__ counter) {
    __shared__ unsigned int sm[16 * 34];
    const int g = blockIdx.x, t = threadIdx.x;
    const int gtid = g * 512 + t;
    if (gtid < BB * MM) fwd[gtid] = 0x7f800000u;  // +inf bits
    if (gtid == 0) { *bsum = 0.0f; *fsum = 0.0f; *counter = 0u; }

    const float* src; unsigned char* dst; float* sq; int gg = g;
    if (g < 2048) { src = x; dst = xq; sq = x2; }
    else          { src = y; dst = yq; sq = y2; gg = g - 2048; }

    const int row16 = t >> 5, k4 = t & 31;
    const int row = gg * 16 + row16;
    f32x4 v = ((const f32x4*)src)[(size_t)row * 32 + k4];
    float s = v.x * v.x + v.y * v.y + v.z * v.z + v.w * v.w;
    unsigned int p32;
    p32  = (unsigned int)__hip_cvt_float_to_fp8(v.x, __HIP_SATFINITE, __HIP_E4M3);
    p32 |= (unsigned int)__hip_cvt_float_to_fp8(v.y, __HIP_SATFINITE, __HIP_E4M3) << 8;
    p32 |= (unsigned int)__hip_cvt_float_to_fp8(v.z, __HIP_SATFINITE, __HIP_E4M3) << 16;
    p32 |= (unsigned int)__hip_cvt_float_to_fp8(v.w, __HIP_SATFINITE, __HIP_E4M3) << 24;
    sm[row16 * 34 + k4] = p32;
    #pragma unroll
    for (int m = 16; m; m >>= 1) s += __shfl_xor(s, m, 64);  // stays in 32-half
    if (k4 == 0) sq[row] = s;
    __syncthreads();

    if (t < 128) {  // 2 halves x 64 lanes of 16B, coalesced
        const int h = t >> 6, l = t & 63;
        const int quad = l >> 4, l15 = l & 15;
        uint4 o;
        o.x = sm[l15 * 34 + (2 * h + 0) * 8 + quad * 2 + 0];
        o.y = sm[l15 * 34 + (2 * h + 0) * 8 + quad * 2 + 1];
        o.z = sm[l15 * 34 + (2 * h + 1) * 8 + quad * 2 + 0];
        o.w = sm[l15 * 34 + (2 * h + 1) * 8 + quad * 2 + 1];
        ((uint4*)(dst + ((size_t)gg * 2 + h) * 1024))[l] = o;
    }
}

// ---------------------------------------------------------------------------
// Main: wave tile 64n x 32m, block 256n x 32m. NO LDS tiles, NO in-loop
// barriers. Cross-batch REGISTER double-buffer: batch b+1's 12 fragment
// loads + batch b's norm loads issue at iteration top; compute consumes
// registers loaded one full batch earlier -> latency hidden by ~800 cyc of
// MFMA+epilogue. ~205 VGPR -> 2 waves/SIMD.
// XCD swizzle: per-XCD contiguous 2048n x 1024m patch -> 384 KB/batch in L2.
// ---------------------------------------------------------------------------
__global__ __launch_bounds__(256, 2)
void chamfer_main(const unsigned char* __restrict__ xq, const unsigned char* __restrict__ yq,
                  const float* __restrict__ x2, const float* __restrict__ y2,
                  unsigned int* __restrict__ fwd, float* __restrict__ bsum) {
    __shared__ float fbuf[BB][32];  // 1 KB

    const int tid  = threadIdx.x;
    const int lane = tid & 63;
    const int wave = tid >> 6;
    const int quad = lane >> 4;
    const int l15  = lane & 15;

    // 2048 blocks: per-XCD patch = 8 nb (2048 n) x 32 mb (1024 m)
    const int id  = blockIdx.x;
    const int xcd = id & 7;
    const int j   = id >> 3;             // 0..255
    const int nb  = ((xcd & 1) << 3) | (j & 7);    // 0..15
    const int mb  = ((xcd >> 1) << 5) | (j >> 3);  // 0..127
    const int n0w = nb * 256 + wave * 64;
    const int m0  = mb * 32;

    const size_t lane16 = (size_t)lane * 16;
    const unsigned char* xbase = xq + (size_t)(n0w >> 4) * 2048 + lane16;
    const unsigned char* ybase = yq + (size_t)(m0 >> 4) * 2048 + lane16;

    for (int i = tid; i < BB * 32; i += 256)
        ((unsigned int*)fbuf)[i] = 0x7f800000u;
    __syncthreads();  // only pre-loop barrier

    long2v fx[2][4][2], fy[2][2][2];
    auto loadb = [&](int b, int s) {
        const unsigned char* xb = xbase + ((size_t)b << 19);  // b*256 groups*2KB
        const unsigned char* yb = ybase + ((size_t)b << 19);
        #pragma unroll
        for (int fi = 0; fi < 4; ++fi)
            #pragma unroll
            for (int h = 0; h < 2; ++h)
                fx[s][fi][h] = *(const long2v*)(xb + ((fi * 2 + h) << 10));
        #pragma unroll
        for (int fj = 0; fj < 2; ++fj)
            #pragma unroll
            for (int h = 0; h < 2; ++h)
                fy[s][fj][h] = *(const long2v*)(yb + ((fj * 2 + h) << 10));
    };
    loadb(0, 0);

    const float INF = __builtin_inff();
    f32x4 bmin[4][2];
    #pragma unroll
    for (int fi = 0; fi < 4; ++fi)
        #pragma unroll
        for (int fj = 0; fj < 2; ++fj)
            bmin[fi][fj] = (f32x4){INF, INF, INF, INF};

    #pragma unroll 2
    for (int b = 0; b < BB; ++b) {
        const int cur = b & 1;
        if (b < BB - 1) loadb(b + 1, cur ^ 1);  // prefetch next batch

        // norms for CURRENT batch (latency covered by the MFMA block below)
        f32x4 x2v[4];
        float y2v[2];
        const float* x2b = x2 + (size_t)b * NN + n0w;
        const float* y2b = y2 + (size_t)b * MM + m0;
        #pragma unroll
        for (int fi = 0; fi < 4; ++fi)
            x2v[fi] = *(const f32x4*)(x2b + fi * 16 + quad * 4);
        y2v[0] = y2b[l15];
        y2v[1] = y2b[16 + l15];

        f32x4 acc[4][2];
        #pragma unroll
        for (int fi = 0; fi < 4; ++fi)
            #pragma unroll
            for (int fj = 0; fj < 2; ++fj)
                acc[fi][fj] = (f32x4){0.f, 0.f, 0.f, 0.f};

        #pragma unroll
        for (int h = 0; h < 2; ++h)
            #pragma unroll
            for (int p = 0; p < 2; ++p)
                #pragma unroll
                for (int fi = 0; fi < 4; ++fi)
                    #pragma unroll
                    for (int fj = 0; fj < 2; ++fj)
                        acc[fi][fj] = __builtin_amdgcn_mfma_f32_16x16x32_fp8_fp8(
                            fx[cur][fi][h][p], fy[cur][fj][h][p], acc[fi][fj], 0, 0, 0);

        // epilogue on SQUARED distances (sqrt deferred; min is monotone)
        float fwd_min[2] = {INF, INF};
        #pragma unroll
        for (int fi = 0; fi < 4; ++fi)
            #pragma unroll
            for (int fj = 0; fj < 2; ++fj)
                #pragma unroll
                for (int e = 0; e < 4; ++e) {
                    float sqv = fmaf(-2.0f, acc[fi][fj][e], x2v[fi][e] + y2v[fj]);
                    bmin[fi][fj][e] = fminf(bmin[fi][fj][e], sqv);
                    fwd_min[fj]     = fminf(fwd_min[fj], sqv);
                }
        #pragma unroll
        for (int fj = 0; fj < 2; ++fj) {
            float v = fwd_min[fj];
            v = fminf(v, __shfl_xor(v, 16, 64));
            v = fminf(v, __shfl_xor(v, 32, 64));
            v = fmaxf(v, 0.0f);  // clamp: uint ordering == float ordering
            if (quad == 0)
                atomicMin((unsigned int*)&fbuf[b][fj * 16 + l15],
                          __float_as_uint(v));
        }
    }
    __syncthreads();  // all 4 waves' fbuf contributions visible

    // flush forward mins: 256 entries, one per thread
    {
        int b = tid >> 5, c = tid & 31;
        atomicMin(&fwd[(size_t)b * MM + m0 + c],
                  __float_as_uint(fbuf[b][c]));
    }

    // backward: sqrt(clamp(min-over-b)), sum, one atomicAdd per wave
    float s = 0.0f;
    #pragma unroll
    for (int fi = 0; fi < 4; ++fi)
        #pragma unroll
        for (int fj = 0; fj < 2; ++fj)
            #pragma unroll
            for (int e = 0; e < 4; ++e)
                s += sqrtf(fmaxf(bmin[fi][fj][e], 0.0f));
    #pragma unroll
    for (int off = 32; off; off >>= 1) s += __shfl_down(s, off, 64);
    if (lane == 0) atomicAdd(bsum, s);
}

// Parallel finalize: 32 blocks x 256 threads, one uint4 per thread.
__global__ __launch_bounds__(256)
void finalize_kernel(const unsigned int* __restrict__ fwd,
                     const float* __restrict__ bsum, float* __restrict__ fsum,
                     unsigned int* __restrict__ counter, float* __restrict__ out) {
    __shared__ float red[4];
    __shared__ int isLast;
    const int tid = threadIdx.x, lane = tid & 63, wave = tid >> 6;
    const int i = blockIdx.x * 256 + tid;
    uint4 u = ((const uint4*)fwd)[i];
    float s = sqrtf(__uint_as_float(u.x)) + sqrtf(__uint_as_float(u.y)) +
              sqrtf(__uint_as_float(u.z)) + sqrtf(__uint_as_float(u.w));
    #pragma unroll
    for (int off = 32; off; off >>= 1) s += __shfl_down(s, off, 64);
    if (lane == 0) red[wave] = s;
    __syncthreads();
    if (tid == 0) {
        atomicAdd(fsum, red[0] + red[1] + red[2] + red[3]);
        __threadfence();
        unsigned int c = atomicAdd(counter, 1u);
        isLast = (c == gridDim.x - 1) ? 1 : 0;
        if (isLast) {
            __threadfence();
            float fs = __hip_atomic_load(fsum, __ATOMIC_RELAXED,
                                         __HIP_MEMORY_SCOPE_AGENT);
            float bs = __hip_atomic_load(bsum, __ATOMIC_RELAXED,
                                         __HIP_MEMORY_SCOPE_AGENT);
            out[0] = fs / (float)(BB * MM) + bs / ((float)NN * (float)MM);
        }
    }
}

extern "C" void kernel_launch(void* const* d_in, const int* in_sizes, int n_in,
                              void* d_out, int out_size, void* d_ws, size_t ws_size,
                              hipStream_t stream) {
    const float* x = (const float*)d_in[0];  // (B,N,D)
    const float* y = (const float*)d_in[1];  // (B,M,D)
    float* out = (float*)d_out;

    char* w = (char*)d_ws;
    unsigned char* xq = (unsigned char*)(w);               // 4 MB fp8 (frag order)
    unsigned char* yq = (unsigned char*)(w + 4194304);     // 4 MB fp8 (frag order)
    float*    x2 = (float*)(w + 8388608);                  // 128 KB
    float*    y2 = (float*)(w + 8519680);                  // 128 KB
    unsigned int* fwd = (unsigned int*)(w + 8650752);      // 128 KB
    float*    bsum = (float*)(w + 8781824);                // 4 B
    float*    fsum = (float*)(w + 8781828);                // 4 B
    unsigned int* counter = (unsigned int*)(w + 8781832);  // 4 B

    prep_all<<<4096, 512, 0, stream>>>(x, y, xq, yq, x2, y2, fwd, bsum, fsum, counter);
    chamfer_main<<<2048, 256, 0, stream>>>(xq, yq, x2, y2, fwd, bsum);
    finalize_kernel<<<32, 256, 0, stream>>>(fwd, bsum, fsum, counter, out);
}

// Round 9
// 124.924 us; speedup vs baseline: 3.5384x; 1.5855x over previous
//
#include <hip/hip_runtime.h>
#include <hip/hip_fp8.h>

#define BB 8
#define NN 4096
#define MM 4096
#define DD 128

typedef float f32x4 __attribute__((ext_vector_type(4)));
typedef long  long2v __attribute__((ext_vector_type(2)));

// ---------------------------------------------------------------------------
// Fragment-ordered fp8 layout (verified R7/R8, absmax 0): for 16-row group g,
// K-half h, the 1KB unit holds lane(quad,l15) -> 16B: row=l15 (within group),
// k=(2h+p)*32+quad*8+(0..7) at byte p*8+(k&7).
// ---------------------------------------------------------------------------

// Prep: one 16-row group per 512-thread block. Coalesced float4 reads + exact
// fp32 norms (32-lane shfl), fp8 via LDS (padded stride 34), coalesced 16B
// fragment-ordered stores. Also inits fwd/accumulators.
__global__ __launch_bounds__(512)
void prep_all(const float* __restrict__ x, const float* __restrict__ y,
              unsigned char* __restrict__ xq, unsigned char* __restrict__ yq,
              float* __restrict__ x2, float* __restrict__ y2,
              unsigned int* __restrict__ fwd, float* __restrict__ bsum,
              float* __restrict__ fsum, unsigned int* __restrict__ counter) {
    __shared__ unsigned int sm[16 * 34];
    const int g = blockIdx.x, t = threadIdx.x;
    const int gtid = g * 512 + t;
    if (gtid < BB * MM) fwd[gtid] = 0x7f800000u;  // +inf bits
    if (gtid == 0) { *bsum = 0.0f; *fsum = 0.0f; *counter = 0u; }

    const float* src; unsigned char* dst; float* sq; int gg = g;
    if (g < 2048) { src = x; dst = xq; sq = x2; }
    else          { src = y; dst = yq; sq = y2; gg = g - 2048; }

    const int row16 = t >> 5, k4 = t & 31;
    const int row = gg * 16 + row16;
    f32x4 v = ((const f32x4*)src)[(size_t)row * 32 + k4];
    float s = v.x * v.x + v.y * v.y + v.z * v.z + v.w * v.w;
    unsigned int p32;
    p32  = (unsigned int)__hip_cvt_float_to_fp8(v.x, __HIP_SATFINITE, __HIP_E4M3);
    p32 |= (unsigned int)__hip_cvt_float_to_fp8(v.y, __HIP_SATFINITE, __HIP_E4M3) << 8;
    p32 |= (unsigned int)__hip_cvt_float_to_fp8(v.z, __HIP_SATFINITE, __HIP_E4M3) << 16;
    p32 |= (unsigned int)__hip_cvt_float_to_fp8(v.w, __HIP_SATFINITE, __HIP_E4M3) << 24;
    sm[row16 * 34 + k4] = p32;
    #pragma unroll
    for (int m = 16; m; m >>= 1) s += __shfl_xor(s, m, 64);  // stays in 32-half
    if (k4 == 0) sq[row] = s;
    __syncthreads();

    if (t < 128) {  // 2 halves x 64 lanes of 16B, coalesced
        const int h = t >> 6, l = t & 63;
        const int quad = l >> 4, l15 = l & 15;
        uint4 o;
        o.x = sm[l15 * 34 + (2 * h + 0) * 8 + quad * 2 + 0];
        o.y = sm[l15 * 34 + (2 * h + 0) * 8 + quad * 2 + 1];
        o.z = sm[l15 * 34 + (2 * h + 1) * 8 + quad * 2 + 0];
        o.w = sm[l15 * 34 + (2 * h + 1) * 8 + quad * 2 + 1];
        ((uint4*)(dst + ((size_t)gg * 2 + h) * 1024))[l] = o;
    }
}

// ---------------------------------------------------------------------------
// Main: wave tile 32n x 32m, block 128n x 32m (4 waves in n). NO LDS tiles,
// NO in-loop barriers, and — key — NO vmem in the loop except the 8 prefetch
// loads for b+1: norms and fwd-mins live in LDS, so the in-order vmcnt wait
// for batch b's fragments sits one full iteration behind its issue (clean
// cross-batch register double-buffer). ~115 VGPR -> 4 waves/SIMD.
// ---------------------------------------------------------------------------
__global__ __launch_bounds__(256, 4)
void chamfer_main(const unsigned char* __restrict__ xq, const unsigned char* __restrict__ yq,
                  const float* __restrict__ x2, const float* __restrict__ y2,
                  unsigned int* __restrict__ fwd, float* __restrict__ bpart) {
    __shared__ float x2s[BB][128];  // 4 KB
    __shared__ float y2s[BB][32];   // 1 KB
    __shared__ float fbuf[BB][32];  // 1 KB
    __shared__ float red[4];

    const int tid  = threadIdx.x;
    const int lane = tid & 63;
    const int wave = tid >> 6;
    const int quad = lane >> 4;
    const int l15  = lane & 15;

    // 4096 blocks; per-XCD m-stripe: xcd = id&7 -> mb = xcd*16 + (j>>5)
    const int id  = blockIdx.x;
    const int xcd = id & 7;
    const int j   = id >> 3;                 // 0..511
    const int nb  = j & 31;                  // 0..31 (128 n each)
    const int mb  = xcd * 16 + (j >> 5);     // 0..127 (32 m each)
    const int n0b = nb * 128;
    const int n0w = n0b + wave * 32;
    const int m0  = mb * 32;

    const size_t lane16 = (size_t)lane * 16;
    const unsigned char* xbase = xq + (size_t)(n0w >> 4) * 2048 + lane16;
    const unsigned char* ybase = yq + (size_t)(m0 >> 4) * 2048 + lane16;

    // stage norms + init fbuf (once), then the only pre-loop barrier
    for (int i = tid; i < BB * 128; i += 256)
        x2s[i >> 7][i & 127] = x2[(size_t)(i >> 7) * NN + n0b + (i & 127)];
    if (tid < BB * 32) {
        y2s[tid >> 5][tid & 31] = y2[(size_t)(tid >> 5) * MM + m0 + (tid & 31)];
        ((unsigned int*)fbuf)[tid] = 0x7f800000u;
    }
    __syncthreads();

    long2v fx[2][2][2], fy[2][2][2];  // [buf][group][half]
    auto loadb = [&](int b, int s) {
        const unsigned char* xb = xbase + ((size_t)b << 19);  // b*256 groups*2KB
        const unsigned char* yb = ybase + ((size_t)b << 19);
        #pragma unroll
        for (int g2 = 0; g2 < 2; ++g2)
            #pragma unroll
            for (int h = 0; h < 2; ++h) {
                fx[s][g2][h] = *(const long2v*)(xb + ((g2 * 2 + h) << 10));
                fy[s][g2][h] = *(const long2v*)(yb + ((g2 * 2 + h) << 10));
            }
    };
    loadb(0, 0);

    const float INF = __builtin_inff();
    f32x4 bmin[2][2];
    #pragma unroll
    for (int fi = 0; fi < 2; ++fi)
        #pragma unroll
        for (int fj = 0; fj < 2; ++fj)
            bmin[fi][fj] = (f32x4){INF, INF, INF, INF};

    #pragma unroll 2
    for (int b = 0; b < BB; ++b) {
        const int cur = b & 1;
        if (b < BB - 1) loadb(b + 1, cur ^ 1);  // the ONLY vmem in the loop

        f32x4 acc[2][2];
        #pragma unroll
        for (int fi = 0; fi < 2; ++fi)
            #pragma unroll
            for (int fj = 0; fj < 2; ++fj)
                acc[fi][fj] = (f32x4){0.f, 0.f, 0.f, 0.f};

        #pragma unroll
        for (int h = 0; h < 2; ++h)
            #pragma unroll
            for (int p = 0; p < 2; ++p)
                #pragma unroll
                for (int fi = 0; fi < 2; ++fi)
                    #pragma unroll
                    for (int fj = 0; fj < 2; ++fj)
                        acc[fi][fj] = __builtin_amdgcn_mfma_f32_16x16x32_fp8_fp8(
                            fx[cur][fi][h][p], fy[cur][fj][h][p], acc[fi][fj], 0, 0, 0);

        // epilogue on SQUARED distances; norms from LDS (no vmem!)
        float y2v[2];
        y2v[0] = y2s[b][l15];
        y2v[1] = y2s[b][16 + l15];
        float fwd_min[2] = {INF, INF};
        #pragma unroll
        for (int fi = 0; fi < 2; ++fi) {
            const f32x4 x2v = *(const f32x4*)&x2s[b][wave * 32 + fi * 16 + quad * 4];
            #pragma unroll
            for (int fj = 0; fj < 2; ++fj)
                #pragma unroll
                for (int e = 0; e < 4; ++e) {
                    float sqv = fmaf(-2.0f, acc[fi][fj][e], x2v[e] + y2v[fj]);
                    bmin[fi][fj][e] = fminf(bmin[fi][fj][e], sqv);
                    fwd_min[fj]     = fminf(fwd_min[fj], sqv);
                }
        }
        #pragma unroll
        for (int fj = 0; fj < 2; ++fj) {
            float v = fwd_min[fj];
            v = fminf(v, __shfl_xor(v, 16, 64));
            v = fminf(v, __shfl_xor(v, 32, 64));
            v = fmaxf(v, 0.0f);  // clamp: uint ordering == float ordering
            if (quad == 0)
                atomicMin((unsigned int*)&fbuf[b][fj * 16 + l15],
                          __float_as_uint(v));
        }
    }
    __syncthreads();  // all 4 waves' fbuf contributions visible

    // flush forward mins: 256 entries, one per thread
    {
        int b = tid >> 5, c = tid & 31;
        atomicMin(&fwd[(size_t)b * MM + m0 + c], __float_as_uint(fbuf[b][c]));
    }

    // backward: sqrt(clamp(min-over-b)), block-reduce, ONE plain store/block
    float s = 0.0f;
    #pragma unroll
    for (int fi = 0; fi < 2; ++fi)
        #pragma unroll
        for (int fj = 0; fj < 2; ++fj)
            #pragma unroll
            for (int e = 0; e < 4; ++e)
                s += sqrtf(fmaxf(bmin[fi][fj][e], 0.0f));
    #pragma unroll
    for (int off = 32; off; off >>= 1) s += __shfl_down(s, off, 64);
    if (lane == 0) red[wave] = s;
    __syncthreads();
    if (tid == 0) bpart[id] = red[0] + red[1] + red[2] + red[3];
}

// Finalize: 32 blocks x 256 threads. fwd: one uint4/thread; bpart: one/thread.
__global__ __launch_bounds__(256)
void finalize_kernel(const unsigned int* __restrict__ fwd,
                     const float* __restrict__ bpart,
                     float* __restrict__ bsum, float* __restrict__ fsum,
                     unsigned int* __restrict__ counter, float* __restrict__ out) {
    __shared__ float redf[4], redb[4];
    __shared__ int isLast;
    const int tid = threadIdx.x, lane = tid & 63, wave = tid >> 6;
    const int gtid = blockIdx.x * 256 + tid;
    uint4 u = ((const uint4*)fwd)[gtid];
    float sf = sqrtf(__uint_as_float(u.x)) + sqrtf(__uint_as_float(u.y)) +
               sqrtf(__uint_as_float(u.z)) + sqrtf(__uint_as_float(u.w));
    float sb = (gtid < 4096) ? bpart[gtid] : 0.0f;
    #pragma unroll
    for (int off = 32; off; off >>= 1) {
        sf += __shfl_down(sf, off, 64);
        sb += __shfl_down(sb, off, 64);
    }
    if (lane == 0) { redf[wave] = sf; redb[wave] = sb; }
    __syncthreads();
    if (tid == 0) {
        atomicAdd(fsum, redf[0] + redf[1] + redf[2] + redf[3]);
        atomicAdd(bsum, redb[0] + redb[1] + redb[2] + redb[3]);
        __threadfence();
        unsigned int c = atomicAdd(counter, 1u);
        isLast = (c == gridDim.x - 1) ? 1 : 0;
        if (isLast) {
            __threadfence();
            float fs = __hip_atomic_load(fsum, __ATOMIC_RELAXED,
                                         __HIP_MEMORY_SCOPE_AGENT);
            float bs = __hip_atomic_load(bsum, __ATOMIC_RELAXED,
                                         __HIP_MEMORY_SCOPE_AGENT);
            out[0] = fs / (float)(BB * MM) + bs / ((float)NN * (float)MM);
        }
    }
}

extern "C" void kernel_launch(void* const* d_in, const int* in_sizes, int n_in,
                              void* d_out, int out_size, void* d_ws, size_t ws_size,
                              hipStream_t stream) {
    const float* x = (const float*)d_in[0];  // (B,N,D)
    const float* y = (const float*)d_in[1];  // (B,M,D)
    float* out = (float*)d_out;

    char* w = (char*)d_ws;
    unsigned char* xq = (unsigned char*)(w);               // 4 MB fp8 (frag order)
    unsigned char* yq = (unsigned char*)(w + 4194304);     // 4 MB fp8 (frag order)
    float*    x2 = (float*)(w + 8388608);                  // 128 KB
    float*    y2 = (float*)(w + 8519680);                  // 128 KB
    unsigned int* fwd = (unsigned int*)(w + 8650752);      // 128 KB
    float*    bpart = (float*)(w + 8781824);               // 16 KB
    float*    bsum = (float*)(w + 8798208);                // 4 B
    float*    fsum = (float*)(w + 8798212);                // 4 B
    unsigned int* counter = (unsigned int*)(w + 8798216);  // 4 B

    prep_all<<<4096, 512, 0, stream>>>(x, y, xq, yq, x2, y2, fwd, bsum, fsum, counter);
    chamfer_main<<<4096, 256, 0, stream>>>(xq, yq, x2, y2, fwd, bpart);
    finalize_kernel<<<32, 256, 0, stream>>>(fwd, bpart, bsum, fsum, counter, out);
}

// Round 10
// 123.825 us; speedup vs baseline: 3.5698x; 1.0089x over previous
//
#include <hip/hip_runtime.h>
#include <hip/hip_fp8.h>

#define BB 8
#define NN 4096
#define MM 4096
#define DD 128

typedef float f32x4 __attribute__((ext_vector_type(4)));
typedef long  long2v __attribute__((ext_vector_type(2)));

// ---------------------------------------------------------------------------
// Fragment-ordered fp8 layout (verified R7/R8/R9, absmax 0): for 16-row group
// g, K-half h, the 1KB unit holds lane(quad,l15) -> 16B: row=l15 (in group),
// k=(2h+p)*32+quad*8+(0..7) at byte p*8+(k&7).
// ---------------------------------------------------------------------------

// Prep (R7-style — measured ~17us faster than the LDS-reorder variant):
// one row per 32 lanes, float4 per thread, exact fp32 norms via shfl,
// scattered 4B fragment-ordered stores. Also inits fwd/accumulators.
__global__ __launch_bounds__(256)
void prep_all(const float* __restrict__ x, const float* __restrict__ y,
              unsigned char* __restrict__ xq, unsigned char* __restrict__ yq,
              float* __restrict__ x2, float* __restrict__ y2,
              unsigned int* __restrict__ fwd, float* __restrict__ bsum,
              float* __restrict__ fsum, unsigned int* __restrict__ counter) {
    int gtid = blockIdx.x * blockDim.x + threadIdx.x;
    if (gtid < BB * MM) fwd[gtid] = 0x7f800000u;  // +inf bits
    if (gtid == 0) { *bsum = 0.0f; *fsum = 0.0f; *counter = 0u; }

    int row = gtid >> 5;
    int k4  = gtid & 31;
    const float* src;
    unsigned char* dst;
    float* sq;
    if (row < BB * NN) {
        src = x; dst = xq; sq = x2;
    } else {
        src = y; dst = yq; sq = y2; row -= BB * NN;
    }
    f32x4 v = ((const f32x4*)src)[(size_t)row * 32 + k4];
    float s = v.x * v.x + v.y * v.y + v.z * v.z + v.w * v.w;
    unsigned int p32;
    p32  = (unsigned int)__hip_cvt_float_to_fp8(v.x, __HIP_SATFINITE, __HIP_E4M3);
    p32 |= (unsigned int)__hip_cvt_float_to_fp8(v.y, __HIP_SATFINITE, __HIP_E4M3) << 8;
    p32 |= (unsigned int)__hip_cvt_float_to_fp8(v.z, __HIP_SATFINITE, __HIP_E4M3) << 16;
    p32 |= (unsigned int)__hip_cvt_float_to_fp8(v.w, __HIP_SATFINITE, __HIP_E4M3) << 24;

    int k    = k4 << 2;
    int kk   = k >> 5;
    int h    = kk >> 1;
    int p    = kk & 1;
    int quad = (k >> 3) & 3;
    size_t dstoff = ((size_t)(row >> 4) * 2 + h) * 1024
                  + (size_t)(quad * 16 + (row & 15)) * 16 + p * 8 + (k & 7);
    *(unsigned int*)(dst + dstoff) = p32;

    #pragma unroll
    for (int m = 16; m; m >>= 1) s += __shfl_xor(s, m, 64);  // stays in 32-half
    if (k4 == 0) sq[row] = s;
}

// ---------------------------------------------------------------------------
// Main: wave tile 32n x 32m, block 128n x 32m. R9 structure preserved (it
// found the 64-VGPR / 8-waves-per-SIMD sweet spot). Change vs R9: the
// per-batch epilogue has NO cross-lane shfl chain and NO branch — each lane
// min-reduces its 8 rows per m-column (pure VALU) and fires a no-return LDS
// ds_min_u32 (4 quads hit the same address; pipelined, no wave stall).
// ---------------------------------------------------------------------------
__global__ __launch_bounds__(256, 4)
void chamfer_main(const unsigned char* __restrict__ xq, const unsigned char* __restrict__ yq,
                  const float* __restrict__ x2, const float* __restrict__ y2,
                  unsigned int* __restrict__ fwd, float* __restrict__ bpart) {
    __shared__ float x2s[BB][128];          // 4 KB
    __shared__ float y2s[BB][32];           // 1 KB
    __shared__ unsigned int fbuf[BB][32];   // 1 KB (fwd min bits per (b,col))
    __shared__ float red[4];

    const int tid  = threadIdx.x;
    const int lane = tid & 63;
    const int wave = tid >> 6;
    const int quad = lane >> 4;
    const int l15  = lane & 15;

    // 4096 blocks; per-XCD m-stripe: xcd = id&7 -> mb = xcd*16 + (j>>5)
    const int id  = blockIdx.x;
    const int xcd = id & 7;
    const int j   = id >> 3;                 // 0..511
    const int nb  = j & 31;                  // 0..31 (128 n each)
    const int mb  = xcd * 16 + (j >> 5);     // 0..127 (32 m each)
    const int n0b = nb * 128;
    const int n0w = n0b + wave * 32;
    const int m0  = mb * 32;

    const size_t lane16 = (size_t)lane * 16;
    const unsigned char* xbase = xq + (size_t)(n0w >> 4) * 2048 + lane16;
    const unsigned char* ybase = yq + (size_t)(m0 >> 4) * 2048 + lane16;

    // stage norms + init fbuf (once), then the only pre-loop barrier
    for (int i = tid; i < BB * 128; i += 256)
        x2s[i >> 7][i & 127] = x2[(size_t)(i >> 7) * NN + n0b + (i & 127)];
    if (tid < BB * 32) {
        y2s[tid >> 5][tid & 31] = y2[(size_t)(tid >> 5) * MM + m0 + (tid & 31)];
        ((unsigned int*)fbuf)[tid] = 0x7f800000u;
    }
    __syncthreads();

    long2v fx[2][2][2], fy[2][2][2];  // [buf][group][half]
    auto loadb = [&](int b, int s) {
        const unsigned char* xb = xbase + ((size_t)b << 19);  // b*256 groups*2KB
        const unsigned char* yb = ybase + ((size_t)b << 19);
        #pragma unroll
        for (int g2 = 0; g2 < 2; ++g2)
            #pragma unroll
            for (int h = 0; h < 2; ++h) {
                fx[s][g2][h] = *(const long2v*)(xb + ((g2 * 2 + h) << 10));
                fy[s][g2][h] = *(const long2v*)(yb + ((g2 * 2 + h) << 10));
            }
    };
    loadb(0, 0);

    const float INF = __builtin_inff();
    f32x4 bmin[2][2];
    #pragma unroll
    for (int fi = 0; fi < 2; ++fi)
        #pragma unroll
        for (int fj = 0; fj < 2; ++fj)
            bmin[fi][fj] = (f32x4){INF, INF, INF, INF};

    #pragma unroll 2
    for (int b = 0; b < BB; ++b) {
        const int cur = b & 1;
        if (b < BB - 1) loadb(b + 1, cur ^ 1);  // the ONLY vmem in the loop

        f32x4 acc[2][2];
        #pragma unroll
        for (int fi = 0; fi < 2; ++fi)
            #pragma unroll
            for (int fj = 0; fj < 2; ++fj)
                acc[fi][fj] = (f32x4){0.f, 0.f, 0.f, 0.f};

        #pragma unroll
        for (int h = 0; h < 2; ++h)
            #pragma unroll
            for (int p = 0; p < 2; ++p)
                #pragma unroll
                for (int fi = 0; fi < 2; ++fi)
                    #pragma unroll
                    for (int fj = 0; fj < 2; ++fj)
                        acc[fi][fj] = __builtin_amdgcn_mfma_f32_16x16x32_fp8_fp8(
                            fx[cur][fi][h][p], fy[cur][fj][h][p], acc[fi][fj], 0, 0, 0);

        // epilogue on SQUARED distances; norms from LDS; NO shfl, NO branch
        float y2v[2];
        y2v[0] = y2s[b][l15];
        y2v[1] = y2s[b][16 + l15];
        float fm[2] = {INF, INF};
        #pragma unroll
        for (int fi = 0; fi < 2; ++fi) {
            const f32x4 x2v = *(const f32x4*)&x2s[b][wave * 32 + fi * 16 + quad * 4];
            #pragma unroll
            for (int fj = 0; fj < 2; ++fj)
                #pragma unroll
                for (int e = 0; e < 4; ++e) {
                    float sqv = fmaf(-2.0f, acc[fi][fj][e], x2v[e] + y2v[fj]);
                    bmin[fi][fj][e] = fminf(bmin[fi][fj][e], sqv);
                    fm[fj]          = fminf(fm[fj], sqv);
                }
        }
        #pragma unroll
        for (int fj = 0; fj < 2; ++fj) {
            // clamp so uint ordering == float ordering; 4 quads same address:
            // no-return ds_min, pipelined in the LDS pipe, no dependency chain
            atomicMin(&fbuf[b][fj * 16 + l15],
                      __float_as_uint(fmaxf(fm[fj], 0.0f)));
        }
    }
    __syncthreads();  // all waves' fbuf contributions visible

    // flush forward mins: 256 entries, one per thread
    {
        int b = tid >> 5, c = tid & 31;
        atomicMin(&fwd[(size_t)b * MM + m0 + c], fbuf[b][c]);
    }

    // backward: sqrt(clamp(min-over-b)), block-reduce, ONE plain store/block
    float s = 0.0f;
    #pragma unroll
    for (int fi = 0; fi < 2; ++fi)
        #pragma unroll
        for (int fj = 0; fj < 2; ++fj)
            #pragma unroll
            for (int e = 0; e < 4; ++e)
                s += sqrtf(fmaxf(bmin[fi][fj][e], 0.0f));
    #pragma unroll
    for (int off = 32; off; off >>= 1) s += __shfl_down(s, off, 64);
    if (lane == 0) red[wave] = s;
    __syncthreads();
    if (tid == 0) bpart[id] = red[0] + red[1] + red[2] + red[3];
}

// Finalize: 32 blocks x 256 threads. fwd: one uint4/thread; bpart: one/thread.
__global__ __launch_bounds__(256)
void finalize_kernel(const unsigned int* __restrict__ fwd,
                     const float* __restrict__ bpart,
                     float* __restrict__ bsum, float* __restrict__ fsum,
                     unsigned int* __restrict__ counter, float* __restrict__ out) {
    __shared__ float redf[4], redb[4];
    __shared__ int isLast;
    const int tid = threadIdx.x, lane = tid & 63, wave = tid >> 6;
    const int gtid = blockIdx.x * 256 + tid;
    uint4 u = ((const uint4*)fwd)[gtid];
    float sf = sqrtf(__uint_as_float(u.x)) + sqrtf(__uint_as_float(u.y)) +
               sqrtf(__uint_as_float(u.z)) + sqrtf(__uint_as_float(u.w));
    float sb = (gtid < 4096) ? bpart[gtid] : 0.0f;
    #pragma unroll
    for (int off = 32; off; off >>= 1) {
        sf += __shfl_down(sf, off, 64);
        sb += __shfl_down(sb, off, 64);
    }
    if (lane == 0) { redf[wave] = sf; redb[wave] = sb; }
    __syncthreads();
    if (tid == 0) {
        atomicAdd(fsum, redf[0] + redf[1] + redf[2] + redf[3]);
        atomicAdd(bsum, redb[0] + redb[1] + redb[2] + redb[3]);
        __threadfence();
        unsigned int c = atomicAdd(counter, 1u);
        isLast = (c == gridDim.x - 1) ? 1 : 0;
        if (isLast) {
            __threadfence();
            float fs = __hip_atomic_load(fsum, __ATOMIC_RELAXED,
                                         __HIP_MEMORY_SCOPE_AGENT);
            float bs = __hip_atomic_load(bsum, __ATOMIC_RELAXED,
                                         __HIP_MEMORY_SCOPE_AGENT);
            out[0] = fs / (float)(BB * MM) + bs / ((float)NN * (float)MM);
        }
    }
}

extern "C" void kernel_launch(void* const* d_in, const int* in_sizes, int n_in,
                              void* d_out, int out_size, void* d_ws, size_t ws_size,
                              hipStream_t stream) {
    const float* x = (const float*)d_in[0];  // (B,N,D)
    const float* y = (const float*)d_in[1];  // (B,M,D)
    float* out = (float*)d_out;

    char* w = (char*)d_ws;
    unsigned char* xq = (unsigned char*)(w);               // 4 MB fp8 (frag order)
    unsigned char* yq = (unsigned char*)(w + 4194304);     // 4 MB fp8 (frag order)
    float*    x2 = (float*)(w + 8388608);                  // 128 KB
    float*    y2 = (float*)(w + 8519680);                  // 128 KB
    unsigned int* fwd = (unsigned int*)(w + 8650752);      // 128 KB
    float*    bpart = (float*)(w + 8781824);               // 16 KB
    float*    bsum = (float*)(w + 8798208);                // 4 B
    float*    fsum = (float*)(w + 8798212);                // 4 B
    unsigned int* counter = (unsigned int*)(w + 8798216);  // 4 B

    // 65536 rows, one per 32 lanes -> 2M threads
    prep_all<<<(2 * BB * NN * 32) / 256, 256, 0, stream>>>(x, y, xq, yq, x2, y2,
                                                           fwd, bsum, fsum, counter);
    chamfer_main<<<4096, 256, 0, stream>>>(xq, yq, x2, y2, fwd, bpart);
    finalize_kernel<<<32, 256, 0, stream>>>(fwd, bpart, bsum, fsum, counter, out);
}